// Round 1
// baseline (951.485 us; speedup 1.0000x reference)
//
#include <hip/hip_runtime.h>
#include <hip/hip_bf16.h>

typedef __attribute__((ext_vector_type(8))) short bf16x8;
typedef __attribute__((ext_vector_type(4))) float f32x4;

#define GLD16(g, s) __builtin_amdgcn_global_load_lds( \
    (const __attribute__((address_space(1))) void*)(g), \
    (__attribute__((address_space(3))) void*)(s), 16, 0, 0)

static constexpr int kB  = 128;
static constexpr int kC  = 1280;
static constexpr int kHW = 256;
static constexpr int BM = 128, BN = 128, BK = 64;

// GEMM: C(M,N) = A(M,K) * Bt(N,K)^T   (A, Bt row-major with ld == K)
// OUT_MODE: 0 = bf16 row-major  addr = z*sC + row*ldC + col
//           1 = f32  row-major  addr = z*sC + row*ldC + col
//           2 = bf16 conv layout addr = (col>>8)*C*HW + row*HW + (col&255)
//           3 = f32 conv layout, val = alpha*(acc [+bias]) + resid[addr]
// BIAS_MODE: 0 = none, 1 = bias[col], 2 = bias[row]
template<int OUT_MODE, int BIAS_MODE>
__global__ __launch_bounds__(256) void gemm_nt(
    const __hip_bfloat16* __restrict__ A,
    const __hip_bfloat16* __restrict__ Bt,
    void* __restrict__ outp,
    const float* __restrict__ bias,
    const float* __restrict__ resid,
    const float* __restrict__ alphap,
    int M, int N, int K,
    long sA, long sB, long sC, int ldC)
{
    __shared__ __hip_bfloat16 As[BM * BK];
    __shared__ __hip_bfloat16 Bs[BN * BK];
    const int t = threadIdx.x;
    const int w = t >> 6;          // wave id 0..3
    const int l = t & 63;          // lane
    const int z = blockIdx.z;
    const long m0 = (long)blockIdx.x * BM;
    const long n0 = (long)blockIdx.y * BN;
    const char* Azb = (const char*)(A + (long)z * sA);
    const char* Bzb = (const char*)(Bt + (long)z * sB);
    const int q = l >> 4, r16 = l & 15;
    const int wr = w >> 1, wc = w & 1;
    const int mw = wr * 64, nw = wc * 64;

    f32x4 acc[4][4] = {};

    for (int k0 = 0; k0 < K; k0 += BK) {
        // stage A tile (128x64 bf16 = 16KB) and B tile via global_load_lds x16B
        #pragma unroll
        for (int i = 0; i < 4; ++i) {
            const int ch = i * 4 + w;            // 16 chunks of 1KB
            const int off = ch * 1024 + l * 16;  // byte offset in tile
            const int row = off >> 7;            // 128B per row (BK*2)
            const int cb = off & 127;
            GLD16(Azb + ((m0 + row) * (long)K + k0) * 2 + cb, (char*)As + ch * 1024);
        }
        #pragma unroll
        for (int i = 0; i < 4; ++i) {
            const int ch = i * 4 + w;
            const int off = ch * 1024 + l * 16;
            const int row = off >> 7;
            const int cb = off & 127;
            GLD16(Bzb + ((n0 + row) * (long)K + k0) * 2 + cb, (char*)Bs + ch * 1024);
        }
        __syncthreads();
        #pragma unroll
        for (int kk = 0; kk < 2; ++kk) {
            bf16x8 av[4], bvf[4];
            #pragma unroll
            for (int mi = 0; mi < 4; ++mi)
                av[mi] = *reinterpret_cast<const bf16x8*>(
                    (const char*)As + (mw + mi * 16 + r16) * 128 + kk * 64 + q * 16);
            #pragma unroll
            for (int ni = 0; ni < 4; ++ni)
                bvf[ni] = *reinterpret_cast<const bf16x8*>(
                    (const char*)Bs + (nw + ni * 16 + r16) * 128 + kk * 64 + q * 16);
            #pragma unroll
            for (int mi = 0; mi < 4; ++mi)
                #pragma unroll
                for (int ni = 0; ni < 4; ++ni)
                    acc[mi][ni] = __builtin_amdgcn_mfma_f32_16x16x32_bf16(
                        av[mi], bvf[ni], acc[mi][ni], 0, 0, 0);
        }
        __syncthreads();
    }

    const float alpha = (OUT_MODE == 3) ? alphap[0] : 0.0f;
    #pragma unroll
    for (int mi = 0; mi < 4; ++mi) {
        #pragma unroll
        for (int ni = 0; ni < 4; ++ni) {
            #pragma unroll
            for (int r = 0; r < 4; ++r) {
                const long row = m0 + mw + mi * 16 + q * 4 + r;  // C/D: row=(l>>4)*4+reg
                const long col = n0 + nw + ni * 16 + r16;        //      col=l&15
                float vv = acc[mi][ni][r];
                if (BIAS_MODE == 1) vv += bias[col];
                if (BIAS_MODE == 2) vv += bias[row];
                if (OUT_MODE == 0) {
                    ((__hip_bfloat16*)outp)[(long)z * sC + row * ldC + col] = __float2bfloat16(vv);
                } else if (OUT_MODE == 1) {
                    ((float*)outp)[(long)z * sC + row * ldC + col] = vv;
                } else if (OUT_MODE == 2) {
                    const long addr = (col >> 8) * (long)(kC * kHW) + row * kHW + (col & 255);
                    ((__hip_bfloat16*)outp)[addr] = __float2bfloat16(vv);
                } else {
                    const long addr = (col >> 8) * (long)(kC * kHW) + row * kHW + (col & 255);
                    ((float*)outp)[addr] = alpha * vv + resid[addr];
                }
            }
        }
    }
}

// x (B, C, HW) f32  ->  xT (B*HW, C) bf16
__global__ __launch_bounds__(256) void transpose_x(
    const float* __restrict__ x, __hip_bfloat16* __restrict__ xT)
{
    __shared__ float tile[64][65];
    const int b = blockIdx.z;
    const int c0 = blockIdx.x * 64;
    const int p0 = blockIdx.y * 64;
    const int tj = threadIdx.x & 63;
    const int ti = threadIdx.x >> 6;
    const float* xb = x + ((long)b * kC + c0) * kHW + p0;
    #pragma unroll
    for (int i = 0; i < 16; ++i) {
        const int c = i * 4 + ti;
        tile[c][tj] = xb[(long)c * kHW + tj];
    }
    __syncthreads();
    __hip_bfloat16* o = xT + ((long)(b * kHW + p0)) * kC + c0;
    #pragma unroll
    for (int i = 0; i < 16; ++i) {
        const int p = i * 4 + ti;
        o[(long)p * kC + tj] = __float2bfloat16(tile[tj][p]);
    }
}

__global__ __launch_bounds__(256) void convert_f32_bf16(
    const float* __restrict__ s, __hip_bfloat16* __restrict__ d)
{
    const int i = (blockIdx.x * 256 + threadIdx.x) * 4;
    const float4 f = *reinterpret_cast<const float4*>(s + i);
    d[i + 0] = __float2bfloat16(f.x);
    d[i + 1] = __float2bfloat16(f.y);
    d[i + 2] = __float2bfloat16(f.z);
    d[i + 3] = __float2bfloat16(f.w);
}

// softmax over the BATCH axis: scores (B, 256, 256) f32 -> attn bf16
__global__ __launch_bounds__(256) void softmax_batch(
    const float* __restrict__ scores, __hip_bfloat16* __restrict__ attn)
{
    const int pos = blockIdx.x * 256 + threadIdx.x;  // 0..65535 = (n,m)
    float m = -3.0e38f, s = 0.0f;
    for (int b = 0; b < kB; ++b) {
        const float v = scores[(long)b * 65536 + pos];
        const float mn = fmaxf(m, v);
        s = s * __expf(m - mn) + __expf(v - mn);
        m = mn;
    }
    const float rinv = 1.0f / s;
    for (int b = 0; b < kB; ++b) {
        const float v = scores[(long)b * 65536 + pos];
        attn[(long)b * 65536 + pos] = __float2bfloat16(__expf(v - m) * rinv);
    }
}

extern "C" void kernel_launch(void* const* d_in, const int* in_sizes, int n_in,
                              void* d_out, int out_size, void* d_ws, size_t ws_size,
                              hipStream_t stream)
{
    const float* x  = (const float*)d_in[0];
    const float* Wk = (const float*)d_in[1];
    const float* bk = (const float*)d_in[2];
    const float* Wq = (const float*)d_in[3];
    const float* bq = (const float*)d_in[4];
    const float* Wv = (const float*)d_in[5];
    const float* bv = (const float*)d_in[6];
    const float* Wr = (const float*)d_in[7];
    const float* br = (const float*)d_in[8];
    const float* al = (const float*)d_in[9];

    char* ws = (char*)d_ws;
    const long SZ = 83886080L;  // 32768*1280*2 bytes
    __hip_bfloat16* xT   = (__hip_bfloat16*)(ws);           // dead after V GEMM
    float*          sc   = (float*)(ws);                    // scores aliases xT (33.5MB)
    __hip_bfloat16* kT   = (__hip_bfloat16*)(ws + SZ);      // dead after scores GEMM
    __hip_bfloat16* attn = (__hip_bfloat16*)(ws + SZ);      // aliases kT (16.8MB)
    __hip_bfloat16* qT   = (__hip_bfloat16*)(ws + 2 * SZ);  // dead after scores GEMM
    __hip_bfloat16* att2 = (__hip_bfloat16*)(ws + 2 * SZ);  // aliases qT
    __hip_bfloat16* vv   = (__hip_bfloat16*)(ws + 3 * SZ);
    __hip_bfloat16* Wkb  = (__hip_bfloat16*)(ws + 4 * SZ);  // 4x 3.3MB bf16 weights
    __hip_bfloat16* Wqb  = Wkb + 1638400;
    __hip_bfloat16* Wvb  = Wkb + 2 * 1638400;
    __hip_bfloat16* Wrb  = Wkb + 3 * 1638400;

    convert_f32_bf16<<<1600, 256, 0, stream>>>(Wk, Wkb);
    convert_f32_bf16<<<1600, 256, 0, stream>>>(Wq, Wqb);
    convert_f32_bf16<<<1600, 256, 0, stream>>>(Wv, Wvb);
    convert_f32_bf16<<<1600, 256, 0, stream>>>(Wr, Wrb);
    transpose_x<<<dim3(20, 4, 128), 256, 0, stream>>>(x, xT);

    // kT (32768,1280) = xT * Wk^T + bk[col]
    gemm_nt<0, 1><<<dim3(256, 10, 1), 256, 0, stream>>>(xT, Wkb, kT, bk, nullptr, nullptr,
        32768, 1280, 1280, 0, 0, 0, 1280);
    gemm_nt<0, 1><<<dim3(256, 10, 1), 256, 0, stream>>>(xT, Wqb, qT, bq, nullptr, nullptr,
        32768, 1280, 1280, 0, 0, 0, 1280);
    // v (B,C,HW) = Wv * xT^T + bv[row]   (conv layout)
    gemm_nt<2, 2><<<dim3(10, 256, 1), 256, 0, stream>>>(Wvb, xT, vv, bv, nullptr, nullptr,
        1280, 32768, 1280, 0, 0, 0, 0);
    // scores (B,256,256) f32 = kT[b] * qT[b]^T
    gemm_nt<1, 0><<<dim3(2, 2, 128), 256, 0, stream>>>(kT, qT, sc, nullptr, nullptr, nullptr,
        256, 256, 1280, 327680, 327680, 65536, 256);
    softmax_batch<<<256, 256, 0, stream>>>(sc, attn);
    // att2 (B,256,1280) = attn[b] * v[b]^T
    gemm_nt<0, 0><<<dim3(2, 10, 128), 256, 0, stream>>>(attn, vv, att2, nullptr, nullptr, nullptr,
        256, 1280, 256, 65536, 327680, 327680, 1280);
    // out f32 (B,C,HW) = alpha*(Wr*att2^T + br[row]) + x
    gemm_nt<3, 2><<<dim3(10, 256, 1), 256, 0, stream>>>(Wrb, att2, d_out, br, x, al,
        1280, 32768, 1280, 0, 0, 0, 0);
}

// Round 2
// 792.555 us; speedup vs baseline: 1.2005x; 1.2005x over previous
//
#include <hip/hip_runtime.h>
#include <hip/hip_bf16.h>

typedef __attribute__((ext_vector_type(8))) short bf16x8;
typedef __attribute__((ext_vector_type(4))) float f32x4;

#define GLD16(g, s) __builtin_amdgcn_global_load_lds( \
    (const __attribute__((address_space(1))) void*)(g), \
    (__attribute__((address_space(3))) void*)(s), 16, 0, 0)

static constexpr int kB  = 128;
static constexpr int kC  = 1280;
static constexpr int kHW = 256;

// Pipelined GEMM: C(M,N) = A(M,K)*Bt(N,K)^T, BM=256 BN=128 BK=64,
// 512 thr = 8 waves (4M x 2N, 64x64 each), 3 LDS slots (48KB each),
// prefetch depth 2, counted vmcnt, XOR-swizzled LDS, setprio MFMA cluster.
// OUT_MODE: 0=bf16 rowmajor, 1=f32 rowmajor, 2=bf16 conv, 3=f32 conv alpha*()+resid
// BIAS_MODE: 0=none, 1=bias[col], 2=bias[row]
template<int OUT_MODE, int BIAS_MODE>
__global__ __launch_bounds__(512, 2) void gemm_p(
    const __hip_bfloat16* __restrict__ A,
    const __hip_bfloat16* __restrict__ Bt,
    void* __restrict__ outp,
    const float* __restrict__ bias,
    const float* __restrict__ resid,
    const float* __restrict__ alphap,
    int M, int N, int K,
    int ldA, int ldB, long sA, long sB, long sC, int ldC)
{
    extern __shared__ char smem[];   // 3 * (32768 A + 16384 B) = 147456
    const int t = threadIdx.x;
    const int w = t >> 6, l = t & 63;
    const int q = l >> 4, r16 = l & 15;
    const int wr = w >> 1, wc = w & 1;
    const int z = blockIdx.z;
    const int nbm = M >> 8, nbn = N >> 7;
    const int nwg = nbm * nbn;
    int f = blockIdx.x;
    {   // bijective XCD swizzle (m204), m-fastest within chunk
        const int q8 = nwg >> 3, r8 = nwg & 7;
        const int xcd = f & 7, rank = f >> 3;
        f = (xcd < r8 ? xcd * (q8 + 1) : r8 * (q8 + 1) + (xcd - r8) * q8) + rank;
    }
    const long m0 = (long)(f % nbm) << 8;
    const long n0 = (long)(f / nbm) << 7;
    const char* Azb = (const char*)(A + (long)z * sA);
    const char* Bzb = (const char*)(Bt + (long)z * sB);

    // stage K-tile k0 into slot: linear LDS dest, inverse-swizzled global src
    auto stage = [&](int k0, int slot) {
        char* base = smem + slot * 49152;
        #pragma unroll
        for (int i = 0; i < 4; ++i) {
            const int d = i * 8192 + t * 16;
            const int row = d >> 7;
            const int cb = (d & 127) ^ ((row & 7) << 4);
            GLD16(Azb + ((m0 + row) * (long)ldA + k0) * 2 + cb, base + d);
        }
        #pragma unroll
        for (int i = 0; i < 2; ++i) {
            const int d = i * 8192 + t * 16;
            const int row = d >> 7;
            const int cb = (d & 127) ^ ((row & 7) << 4);
            GLD16(Bzb + ((n0 + row) * (long)ldB + k0) * 2 + cb, base + 32768 + d);
        }
    };

    f32x4 acc[4][4] = {};
    const int nK = K >> 6;
    stage(0, 0);
    if (nK > 1) stage(64, 1);
    if (nK > 2) stage(128, 2);

    int slot = 0;
    for (int tk = 0; tk < nK; ++tk) {
        // counted wait: own S(tk) loads retired; up to 12 (S(tk+1),S(tk+2)) in flight
        if (tk + 2 < nK)      { asm volatile("s_waitcnt vmcnt(12)" ::: "memory"); }
        else if (tk + 1 < nK) { asm volatile("s_waitcnt vmcnt(6)" ::: "memory"); }
        else                  { asm volatile("s_waitcnt vmcnt(0)" ::: "memory"); }
        __builtin_amdgcn_sched_barrier(0);
        __builtin_amdgcn_s_barrier();          // tile tk visible to all waves
        __builtin_amdgcn_sched_barrier(0);

        const char* As = smem + slot * 49152;
        const char* Bs = As + 32768;
        bf16x8 av[4][2], bv[4][2];
        #pragma unroll
        for (int mi = 0; mi < 4; ++mi)
            #pragma unroll
            for (int kk = 0; kk < 2; ++kk) {
                const int row = wr * 64 + mi * 16 + r16;
                av[mi][kk] = *reinterpret_cast<const bf16x8*>(
                    As + ((row * 128 + kk * 64 + q * 16) ^ ((row & 7) << 4)));
            }
        #pragma unroll
        for (int ni = 0; ni < 4; ++ni)
            #pragma unroll
            for (int kk = 0; kk < 2; ++kk) {
                const int row = wc * 64 + ni * 16 + r16;
                bv[ni][kk] = *reinterpret_cast<const bf16x8*>(
                    Bs + ((row * 128 + kk * 64 + q * 16) ^ ((row & 7) << 4)));
            }
        asm volatile("s_waitcnt lgkmcnt(0)" ::: "memory");
        __builtin_amdgcn_sched_barrier(0);
        __builtin_amdgcn_s_barrier();          // all waves done reading slot
        __builtin_amdgcn_sched_barrier(0);
        if (tk + 3 < nK) stage((tk + 3) << 6, slot);  // overwrite freed slot
        __builtin_amdgcn_sched_barrier(0);

        __builtin_amdgcn_s_setprio(1);
        #pragma unroll
        for (int kk = 0; kk < 2; ++kk)
            #pragma unroll
            for (int mi = 0; mi < 4; ++mi)
                #pragma unroll
                for (int ni = 0; ni < 4; ++ni)
                    acc[mi][ni] = __builtin_amdgcn_mfma_f32_16x16x32_bf16(
                        av[mi][kk], bv[ni][kk], acc[mi][ni], 0, 0, 0);
        __builtin_amdgcn_s_setprio(0);
        slot = (slot == 2) ? 0 : slot + 1;
    }

    const float alpha = (OUT_MODE == 3) ? alphap[0] : 0.0f;
    #pragma unroll
    for (int mi = 0; mi < 4; ++mi) {
        #pragma unroll
        for (int ni = 0; ni < 4; ++ni) {
            #pragma unroll
            for (int r = 0; r < 4; ++r) {
                const long row = m0 + wr * 64 + mi * 16 + q * 4 + r;
                const long col = n0 + wc * 64 + ni * 16 + r16;
                float vv = acc[mi][ni][r];
                if (BIAS_MODE == 1) vv += bias[col];
                if (BIAS_MODE == 2) vv += bias[row];
                if (OUT_MODE == 0) {
                    ((__hip_bfloat16*)outp)[(long)z * sC + row * ldC + col] = __float2bfloat16(vv);
                } else if (OUT_MODE == 1) {
                    ((float*)outp)[(long)z * sC + row * ldC + col] = vv;
                } else if (OUT_MODE == 2) {
                    const long addr = (col >> 8) * (long)(kC * kHW) + row * kHW + (col & 255);
                    ((__hip_bfloat16*)outp)[addr] = __float2bfloat16(vv);
                } else {
                    const long addr = (col >> 8) * (long)(kC * kHW) + row * kHW + (col & 255);
                    ((float*)outp)[addr] = alpha * vv + resid[addr];
                }
            }
        }
    }
}

// x (B, C, HW) f32  ->  xT (B*HW, C) bf16
__global__ __launch_bounds__(256) void transpose_x(
    const float* __restrict__ x, __hip_bfloat16* __restrict__ xT)
{
    __shared__ float tile[64][65];
    const int b = blockIdx.z;
    const int c0 = blockIdx.x * 64;
    const int p0 = blockIdx.y * 64;
    const int tj = threadIdx.x & 63;
    const int ti = threadIdx.x >> 6;
    const float* xb = x + ((long)b * kC + c0) * kHW + p0;
    #pragma unroll
    for (int i = 0; i < 16; ++i) {
        const int c = i * 4 + ti;
        tile[c][tj] = xb[(long)c * kHW + tj];
    }
    __syncthreads();
    __hip_bfloat16* o = xT + ((long)(b * kHW + p0)) * kC + c0;
    #pragma unroll
    for (int i = 0; i < 16; ++i) {
        const int p = i * 4 + ti;
        o[(long)p * kC + tj] = __float2bfloat16(tile[tj][p]);
    }
}

__global__ __launch_bounds__(256) void convert_f32_bf16(
    const float* __restrict__ s, __hip_bfloat16* __restrict__ d)
{
    const int i = (blockIdx.x * 256 + threadIdx.x) * 4;
    const float4 f = *reinterpret_cast<const float4*>(s + i);
    d[i + 0] = __float2bfloat16(f.x);
    d[i + 1] = __float2bfloat16(f.y);
    d[i + 2] = __float2bfloat16(f.z);
    d[i + 3] = __float2bfloat16(f.w);
}

__global__ __launch_bounds__(256) void concat_bias(
    const float* __restrict__ bk, const float* __restrict__ bq, float* __restrict__ bc)
{
    const int i = blockIdx.x * 256 + threadIdx.x;  // grid 10*256 = 2560
    bc[i] = (i < 1280) ? bk[i] : bq[i - 1280];
}

// softmax over BATCH axis: scores (B,256,256) f32 -> attn bf16
__global__ __launch_bounds__(256) void softmax_batch(
    const float* __restrict__ scores, __hip_bfloat16* __restrict__ attn)
{
    const int pos = blockIdx.x * 256 + threadIdx.x;
    float m = -3.0e38f, s = 0.0f;
    for (int b = 0; b < kB; ++b) {
        const float v = scores[(long)b * 65536 + pos];
        const float mn = fmaxf(m, v);
        s = s * __expf(m - mn) + __expf(v - mn);
        m = mn;
    }
    const float rinv = 1.0f / s;
    for (int b = 0; b < kB; ++b) {
        const float v = scores[(long)b * 65536 + pos];
        attn[(long)b * 65536 + pos] = __float2bfloat16(__expf(v - m) * rinv);
    }
}

extern "C" void kernel_launch(void* const* d_in, const int* in_sizes, int n_in,
                              void* d_out, int out_size, void* d_ws, size_t ws_size,
                              hipStream_t stream)
{
    const float* x  = (const float*)d_in[0];
    const float* Wk = (const float*)d_in[1];
    const float* bk = (const float*)d_in[2];
    const float* Wq = (const float*)d_in[3];
    const float* bq = (const float*)d_in[4];
    const float* Wv = (const float*)d_in[5];
    const float* bv = (const float*)d_in[6];
    const float* Wr = (const float*)d_in[7];
    const float* br = (const float*)d_in[8];
    const float* al = (const float*)d_in[9];

    char* ws = (char*)d_ws;
    __hip_bfloat16* xT   = (__hip_bfloat16*)(ws);               // 83.9MB; dead after V GEMM
    float*          sc   = (float*)(ws);                        // aliases xT (33.5MB)
    __hip_bfloat16* kqT  = (__hip_bfloat16*)(ws + 83886080L);   // (32768,2560) 167.8MB
    __hip_bfloat16* attn = (__hip_bfloat16*)(ws + 83886080L);   // aliases kqT (16.8MB)
    __hip_bfloat16* att2 = (__hip_bfloat16*)(ws + 100663296L);  // aliases kqT tail (83.9MB)
    __hip_bfloat16* vv   = (__hip_bfloat16*)(ws + 251658240L);  // 83.9MB
    __hip_bfloat16* Wcatb= (__hip_bfloat16*)(ws + 335544320L);  // (2560,1280)
    __hip_bfloat16* Wvb  = Wcatb + 2560 * 1280;
    __hip_bfloat16* Wrb  = Wvb + 1280 * 1280;
    float*          bcat = (float*)(ws + 348651520L);           // 2560 f32

    const int SMEM = 147456;
    hipFuncSetAttribute((const void*)gemm_p<0,1>, hipFuncAttributeMaxDynamicSharedMemorySize, SMEM);
    hipFuncSetAttribute((const void*)gemm_p<2,2>, hipFuncAttributeMaxDynamicSharedMemorySize, SMEM);
    hipFuncSetAttribute((const void*)gemm_p<1,0>, hipFuncAttributeMaxDynamicSharedMemorySize, SMEM);
    hipFuncSetAttribute((const void*)gemm_p<0,0>, hipFuncAttributeMaxDynamicSharedMemorySize, SMEM);
    hipFuncSetAttribute((const void*)gemm_p<3,2>, hipFuncAttributeMaxDynamicSharedMemorySize, SMEM);

    convert_f32_bf16<<<1600, 256, 0, stream>>>(Wk, Wcatb);
    convert_f32_bf16<<<1600, 256, 0, stream>>>(Wq, Wcatb + 1638400);
    convert_f32_bf16<<<1600, 256, 0, stream>>>(Wv, Wvb);
    convert_f32_bf16<<<1600, 256, 0, stream>>>(Wr, Wrb);
    concat_bias<<<10, 256, 0, stream>>>(bk, bq, bcat);
    transpose_x<<<dim3(20, 4, 128), 256, 0, stream>>>(x, xT);

    // fused K|Q: kqT (32768, 2560) = xT * Wcat^T + bcat[col]
    gemm_p<0, 1><<<dim3(2560, 1, 1), 512, SMEM, stream>>>(xT, Wcatb, kqT, bcat, nullptr, nullptr,
        32768, 2560, 1280, 1280, 1280, 0, 0, 0, 2560);
    // v (B,C,HW) = Wv * xT^T + bv[row]
    gemm_p<2, 2><<<dim3(1280, 1, 1), 512, SMEM, stream>>>(Wvb, xT, vv, bv, nullptr, nullptr,
        1280, 32768, 1280, 1280, 1280, 0, 0, 0, 0);
    // scores (B,256,256) f32 = kT[b] * qT[b]^T   (kT = kqT cols 0:1280, qT = cols 1280:2560)
    gemm_p<1, 0><<<dim3(2, 1, 128), 512, SMEM, stream>>>(kqT, kqT + 1280, sc, nullptr, nullptr, nullptr,
        256, 256, 1280, 2560, 2560, 655360, 655360, 65536, 256);
    softmax_batch<<<256, 256, 0, stream>>>(sc, attn);
    // att2 (B,256,1280) = attn[b] * v[b]^T
    gemm_p<0, 0><<<dim3(10, 1, 128), 512, SMEM, stream>>>(attn, vv, att2, nullptr, nullptr, nullptr,
        256, 1280, 256, 256, 256, 65536, 327680, 327680, 1280);
    // out f32 (B,C,HW) = alpha*(Wr*att2^T + br[row]) + x
    gemm_p<3, 2><<<dim3(1280, 1, 1), 512, SMEM, stream>>>(Wrb, att2, d_out, br, x, al,
        1280, 32768, 1280, 1280, 1280, 0, 0, 0, 0);
}

// Round 4
// 761.007 us; speedup vs baseline: 1.2503x; 1.0415x over previous
//
#include <hip/hip_runtime.h>
#include <hip/hip_bf16.h>

typedef __attribute__((ext_vector_type(8))) short bf16x8;
typedef __attribute__((ext_vector_type(4))) float f32x4;

#define GLD16(g, s) __builtin_amdgcn_global_load_lds( \
    (const __attribute__((address_space(1))) void*)(g), \
    (__attribute__((address_space(3))) void*)(s), 16, 0, 0)

static constexpr int kB  = 128;
static constexpr int kC  = 1280;
static constexpr int kHW = 256;

// Pipelined GEMM: C(M,N) = A(M,K)*Bt(N,K)^T, BM=256 BN=128 BK=64,
// 512 thr = 8 waves (4M x 2N, 64x64 each), 3 LDS slots (48KB each),
// prefetch depth 2, counted vmcnt, XOR-swizzled LDS, setprio MFMA cluster.
// OUT_MODE: 0=bf16 rowmajor, 1=f32 rowmajor, 2=bf16 conv, 3=f32 conv alpha*()+resid
// BIAS_MODE: 0=none, 1=bias[col], 2=bias[row]
// ORDER: 0 = m-fastest (consecutive blocks share B panel; use when B is the
//        large operand), 1 = n-fastest (share A panel; use when A is large).
template<int OUT_MODE, int BIAS_MODE, int ORDER>
__global__ __launch_bounds__(512, 2) void gemm_p(
    const __hip_bfloat16* __restrict__ A,
    const __hip_bfloat16* __restrict__ Bt,
    void* __restrict__ outp,
    const float* __restrict__ bias,
    const float* __restrict__ resid,
    const float* __restrict__ alphap,
    int M, int N, int K,
    int ldA, int ldB, long sA, long sB, long sC, int ldC)
{
    extern __shared__ char smem[];   // 3 * (32768 A + 16384 B) = 147456
    const int t = threadIdx.x;
    const int w = t >> 6, l = t & 63;
    const int q = l >> 4, r16 = l & 15;
    const int wr = w >> 1, wc = w & 1;
    const int z = blockIdx.z;
    const int nbm = M >> 8, nbn = N >> 7;
    const int nwg = nbm * nbn;
    int f = blockIdx.x;
    {   // bijective XCD swizzle (m204): each XCD owns a contiguous f-chunk
        const int q8 = nwg >> 3, r8 = nwg & 7;
        const int xcd = f & 7, rank = f >> 3;
        f = (xcd < r8 ? xcd * (q8 + 1) : r8 * (q8 + 1) + (xcd - r8) * q8) + rank;
    }
    long m0, n0;
    if (ORDER == 0) { m0 = (long)(f % nbm) << 8; n0 = (long)(f / nbm) << 7; }
    else            { n0 = (long)(f % nbn) << 7; m0 = (long)(f / nbn) << 8; }
    const char* Azb = (const char*)(A + (long)z * sA);
    const char* Bzb = (const char*)(Bt + (long)z * sB);

    // stage K-tile k0 into slot: linear LDS dest, inverse-swizzled global src
    auto stage = [&](int k0, int slot) {
        char* base = smem + slot * 49152;
        #pragma unroll
        for (int i = 0; i < 4; ++i) {
            const int d = i * 8192 + t * 16;
            const int row = d >> 7;
            const int cb = (d & 127) ^ ((row & 7) << 4);
            GLD16(Azb + ((m0 + row) * (long)ldA + k0) * 2 + cb, base + d);
        }
        #pragma unroll
        for (int i = 0; i < 2; ++i) {
            const int d = i * 8192 + t * 16;
            const int row = d >> 7;
            const int cb = (d & 127) ^ ((row & 7) << 4);
            GLD16(Bzb + ((n0 + row) * (long)ldB + k0) * 2 + cb, base + 32768 + d);
        }
    };

    f32x4 acc[4][4] = {};
    const int nK = K >> 6;
    stage(0, 0);
    if (nK > 1) stage(64, 1);
    if (nK > 2) stage(128, 2);

    int slot = 0;
    for (int tk = 0; tk < nK; ++tk) {
        // counted wait: own S(tk) loads retired; up to 12 (S(tk+1),S(tk+2)) in flight
        if (tk + 2 < nK)      { asm volatile("s_waitcnt vmcnt(12)" ::: "memory"); }
        else if (tk + 1 < nK) { asm volatile("s_waitcnt vmcnt(6)" ::: "memory"); }
        else                  { asm volatile("s_waitcnt vmcnt(0)" ::: "memory"); }
        __builtin_amdgcn_sched_barrier(0);
        __builtin_amdgcn_s_barrier();          // tile tk visible to all waves
        __builtin_amdgcn_sched_barrier(0);

        const char* As = smem + slot * 49152;
        const char* Bs = As + 32768;
        bf16x8 av[4][2], bv[4][2];
        #pragma unroll
        for (int mi = 0; mi < 4; ++mi)
            #pragma unroll
            for (int kk = 0; kk < 2; ++kk) {
                const int row = wr * 64 + mi * 16 + r16;
                av[mi][kk] = *reinterpret_cast<const bf16x8*>(
                    As + ((row * 128 + kk * 64 + q * 16) ^ ((row & 7) << 4)));
            }
        #pragma unroll
        for (int ni = 0; ni < 4; ++ni)
            #pragma unroll
            for (int kk = 0; kk < 2; ++kk) {
                const int row = wc * 64 + ni * 16 + r16;
                bv[ni][kk] = *reinterpret_cast<const bf16x8*>(
                    Bs + ((row * 128 + kk * 64 + q * 16) ^ ((row & 7) << 4)));
            }
        asm volatile("s_waitcnt lgkmcnt(0)" ::: "memory");
        __builtin_amdgcn_sched_barrier(0);
        __builtin_amdgcn_s_barrier();          // all waves done reading slot
        __builtin_amdgcn_sched_barrier(0);
        if (tk + 3 < nK) stage((tk + 3) << 6, slot);  // overwrite freed slot
        __builtin_amdgcn_sched_barrier(0);

        __builtin_amdgcn_s_setprio(1);
        #pragma unroll
        for (int kk = 0; kk < 2; ++kk)
            #pragma unroll
            for (int mi = 0; mi < 4; ++mi)
                #pragma unroll
                for (int ni = 0; ni < 4; ++ni)
                    acc[mi][ni] = __builtin_amdgcn_mfma_f32_16x16x32_bf16(
                        av[mi][kk], bv[ni][kk], acc[mi][ni], 0, 0, 0);
        __builtin_amdgcn_s_setprio(0);
        slot = (slot == 2) ? 0 : slot + 1;
    }

    const float alpha = (OUT_MODE == 3) ? alphap[0] : 0.0f;
    #pragma unroll
    for (int mi = 0; mi < 4; ++mi) {
        #pragma unroll
        for (int ni = 0; ni < 4; ++ni) {
            #pragma unroll
            for (int r = 0; r < 4; ++r) {
                const long row = m0 + wr * 64 + mi * 16 + q * 4 + r;
                const long col = n0 + wc * 64 + ni * 16 + r16;
                float vv = acc[mi][ni][r];
                if (BIAS_MODE == 1) vv += bias[col];
                if (BIAS_MODE == 2) vv += bias[row];
                if (OUT_MODE == 0) {
                    ((__hip_bfloat16*)outp)[(long)z * sC + row * ldC + col] = __float2bfloat16(vv);
                } else if (OUT_MODE == 1) {
                    ((float*)outp)[(long)z * sC + row * ldC + col] = vv;
                } else if (OUT_MODE == 2) {
                    const long addr = (col >> 8) * (long)(kC * kHW) + row * kHW + (col & 255);
                    ((__hip_bfloat16*)outp)[addr] = __float2bfloat16(vv);
                } else {
                    const long addr = (col >> 8) * (long)(kC * kHW) + row * kHW + (col & 255);
                    ((float*)outp)[addr] = alpha * vv + resid[addr];
                }
            }
        }
    }
}

// x (B, C, HW) f32  ->  xT (B*HW, C) bf16
__global__ __launch_bounds__(256) void transpose_x(
    const float* __restrict__ x, __hip_bfloat16* __restrict__ xT)
{
    __shared__ float tile[64][65];
    const int b = blockIdx.z;
    const int c0 = blockIdx.x * 64;
    const int p0 = blockIdx.y * 64;
    const int tj = threadIdx.x & 63;
    const int ti = threadIdx.x >> 6;
    const float* xb = x + ((long)b * kC + c0) * kHW + p0;
    #pragma unroll
    for (int i = 0; i < 16; ++i) {
        const int c = i * 4 + ti;
        tile[c][tj] = xb[(long)c * kHW + tj];
    }
    __syncthreads();
    __hip_bfloat16* o = xT + ((long)(b * kHW + p0)) * kC + c0;
    #pragma unroll
    for (int i = 0; i < 16; ++i) {
        const int p = i * 4 + ti;
        o[(long)p * kC + tj] = __float2bfloat16(tile[tj][p]);
    }
}

__global__ __launch_bounds__(256) void convert_f32_bf16(
    const float* __restrict__ s, __hip_bfloat16* __restrict__ d)
{
    const int i = (blockIdx.x * 256 + threadIdx.x) * 4;
    const float4 f = *reinterpret_cast<const float4*>(s + i);
    d[i + 0] = __float2bfloat16(f.x);
    d[i + 1] = __float2bfloat16(f.y);
    d[i + 2] = __float2bfloat16(f.z);
    d[i + 3] = __float2bfloat16(f.w);
}

__global__ __launch_bounds__(256) void concat_bias(
    const float* __restrict__ bk, const float* __restrict__ bq, float* __restrict__ bc)
{
    const int i = blockIdx.x * 256 + threadIdx.x;  // grid 10*256 = 2560
    bc[i] = (i < 1280) ? bk[i] : bq[i - 1280];
}

// softmax over BATCH axis: scores (B,256,256) f32 -> attn bf16
__global__ __launch_bounds__(256) void softmax_batch(
    const float* __restrict__ scores, __hip_bfloat16* __restrict__ attn)
{
    const int pos = blockIdx.x * 256 + threadIdx.x;
    float m = -3.0e38f, s = 0.0f;
    for (int b = 0; b < kB; ++b) {
        const float v = scores[(long)b * 65536 + pos];
        const float mn = fmaxf(m, v);
        s = s * __expf(m - mn) + __expf(v - mn);
        m = mn;
    }
    const float rinv = 1.0f / s;
    for (int b = 0; b < kB; ++b) {
        const float v = scores[(long)b * 65536 + pos];
        attn[(long)b * 65536 + pos] = __float2bfloat16(__expf(v - m) * rinv);
    }
}

extern "C" void kernel_launch(void* const* d_in, const int* in_sizes, int n_in,
                              void* d_out, int out_size, void* d_ws, size_t ws_size,
                              hipStream_t stream)
{
    const float* x  = (const float*)d_in[0];
    const float* Wk = (const float*)d_in[1];
    const float* bk = (const float*)d_in[2];
    const float* Wq = (const float*)d_in[3];
    const float* bq = (const float*)d_in[4];
    const float* Wv = (const float*)d_in[5];
    const float* bv = (const float*)d_in[6];
    const float* Wr = (const float*)d_in[7];
    const float* br = (const float*)d_in[8];
    const float* al = (const float*)d_in[9];

    char* ws = (char*)d_ws;
    __hip_bfloat16* xT   = (__hip_bfloat16*)(ws);               // 83.9MB; dead after V GEMM
    float*          sc   = (float*)(ws);                        // aliases xT (33.5MB)
    __hip_bfloat16* kqT  = (__hip_bfloat16*)(ws + 83886080L);   // (32768,2560) 167.8MB
    __hip_bfloat16* attn = (__hip_bfloat16*)(ws + 83886080L);   // aliases kqT (16.8MB)
    __hip_bfloat16* att2 = (__hip_bfloat16*)(ws + 100663296L);  // aliases kqT tail (83.9MB)
    __hip_bfloat16* vv   = (__hip_bfloat16*)(ws + 251658240L);  // 83.9MB
    __hip_bfloat16* Wcatb= (__hip_bfloat16*)(ws + 335544320L);  // (2560,1280)
    __hip_bfloat16* Wvb  = Wcatb + 2560 * 1280;
    __hip_bfloat16* Wrb  = Wvb + 1280 * 1280;
    float*          bcat = (float*)(ws + 348651520L);           // 2560 f32

    const int SMEM = 147456;
    hipFuncSetAttribute((const void*)gemm_p<0,1,1>, hipFuncAttributeMaxDynamicSharedMemorySize, SMEM);
    hipFuncSetAttribute((const void*)gemm_p<2,2,0>, hipFuncAttributeMaxDynamicSharedMemorySize, SMEM);
    hipFuncSetAttribute((const void*)gemm_p<1,0,0>, hipFuncAttributeMaxDynamicSharedMemorySize, SMEM);
    hipFuncSetAttribute((const void*)gemm_p<0,0,0>, hipFuncAttributeMaxDynamicSharedMemorySize, SMEM);
    hipFuncSetAttribute((const void*)gemm_p<3,2,0>, hipFuncAttributeMaxDynamicSharedMemorySize, SMEM);

    convert_f32_bf16<<<1600, 256, 0, stream>>>(Wk, Wcatb);
    convert_f32_bf16<<<1600, 256, 0, stream>>>(Wq, Wcatb + 1638400);
    convert_f32_bf16<<<1600, 256, 0, stream>>>(Wv, Wvb);
    convert_f32_bf16<<<1600, 256, 0, stream>>>(Wr, Wrb);
    concat_bias<<<10, 256, 0, stream>>>(bk, bq, bcat);
    transpose_x<<<dim3(20, 4, 128), 256, 0, stream>>>(x, xT);

    // fused K|Q: kqT (32768, 2560) = xT * Wcat^T + bcat[col]
    // A (xT, 84MB) is the large operand -> ORDER=1 (n-fastest, share A panel in L2)
    gemm_p<0, 1, 1><<<dim3(2560, 1, 1), 512, SMEM, stream>>>(xT, Wcatb, kqT, bcat, nullptr, nullptr,
        32768, 2560, 1280, 1280, 1280, 0, 0, 0, 2560);
    // v (B,C,HW) = Wv * xT^T + bv[row];  B (xT) large -> ORDER=0 (share B panel)
    gemm_p<2, 2, 0><<<dim3(1280, 1, 1), 512, SMEM, stream>>>(Wvb, xT, vv, bv, nullptr, nullptr,
        1280, 32768, 1280, 1280, 1280, 0, 0, 0, 0);
    // scores (B,256,256) f32 = kT[b] * qT[b]^T   (kT = kqT cols 0:1280, qT = cols 1280:2560)
    gemm_p<1, 0, 0><<<dim3(2, 1, 128), 512, SMEM, stream>>>(kqT, kqT + 1280, sc, nullptr, nullptr, nullptr,
        256, 256, 1280, 2560, 2560, 655360, 655360, 65536, 256);
    softmax_batch<<<256, 256, 0, stream>>>(sc, attn);
    // att2 (B,256,1280) = attn[b] * v[b]^T
    gemm_p<0, 0, 0><<<dim3(10, 1, 128), 512, SMEM, stream>>>(attn, vv, att2, nullptr, nullptr, nullptr,
        256, 1280, 256, 256, 256, 65536, 327680, 327680, 1280);
    // out f32 (B,C,HW) = alpha*(Wr*att2^T + br[row]) + x;  B (att2) large -> ORDER=0
    gemm_p<3, 2, 0><<<dim3(1280, 1, 1), 512, SMEM, stream>>>(Wrb, att2, d_out, br, x, al,
        1280, 32768, 1280, 1280, 1280, 0, 0, 0, 0);
}

// Round 5
// 677.685 us; speedup vs baseline: 1.4040x; 1.1230x over previous
//
#include <hip/hip_runtime.h>
#include <hip/hip_bf16.h>

typedef __attribute__((ext_vector_type(8))) short bf16x8;
typedef __attribute__((ext_vector_type(4))) float f32x4;

#define GLD16(g, s) __builtin_amdgcn_global_load_lds( \
    (const __attribute__((address_space(1))) void*)(g), \
    (__attribute__((address_space(3))) void*)(s), 16, 0, 0)

#define SBAR() __builtin_amdgcn_sched_barrier(0)
#define WAIT_LGKM(n) do { asm volatile("s_waitcnt lgkmcnt(" #n ")" ::: "memory"); SBAR(); } while (0)

static constexpr int kB  = 128;
static constexpr int kC  = 1280;
static constexpr int kHW = 256;

// Phase-interleaved GEMM: C(M,N) = A(M,K)*Bt(N,K)^T.
// BM=BN=256, BK=64; 512 thr = 8 waves (2M x 4N), wave tile 128x64.
// 2 LDS slots x 64KB (A 256x64 + B 256x64). One s_barrier + vmcnt(0) per
// K-tile (staging issued a full tile ahead); within the tile, 4 MFMA
// quadrants (16 MFMA each) interleaved with next-quadrant ds_reads via
// counted lgkmcnt. XOR-swizzled LDS (both sides), setprio MFMA clusters.
// OUT_MODE: 0=bf16 rowmajor, 1=f32 rowmajor, 2=bf16 conv, 3=f32 conv alpha*()+resid
// BIAS_MODE: 0=none, 1=bias[col], 2=bias[row]
// ORDER: 0 = m-fastest (B operand large), 1 = n-fastest (A operand large)
template<int OUT_MODE, int BIAS_MODE, int ORDER>
__global__ __launch_bounds__(512, 2) void gemm_q(
    const __hip_bfloat16* __restrict__ A,
    const __hip_bfloat16* __restrict__ Bt,
    void* __restrict__ outp,
    const float* __restrict__ bias,
    const float* __restrict__ resid,
    const float* __restrict__ alphap,
    int M, int N, int K,
    int ldA, int ldB, long sA, long sB, long sC, int ldC)
{
    extern __shared__ char smem[];   // 2 slots x 65536 = 131072
    const int t = threadIdx.x;
    const int w = t >> 6, l = t & 63;
    const int q = l >> 4, r16 = l & 15;
    const int wr = w >> 2, wc = w & 3;   // 2M x 4N waves
    const int z = blockIdx.z;
    const int nbm = M >> 8, nbn = N >> 8;
    const int nwg = nbm * nbn;
    int f = blockIdx.x;
    {   // bijective XCD swizzle (m204)
        const int q8 = nwg >> 3, r8 = nwg & 7;
        const int xcd = f & 7, rank = f >> 3;
        f = (xcd < r8 ? xcd * (q8 + 1) : r8 * (q8 + 1) + (xcd - r8) * q8) + rank;
    }
    long m0, n0;
    if (ORDER == 0) { m0 = (long)(f % nbm) << 8; n0 = (long)(f / nbm) << 8; }
    else            { n0 = (long)(f % nbn) << 8; m0 = (long)(f / nbn) << 8; }
    const char* Azb = (const char*)(A + (long)z * sA);
    const char* Bzb = (const char*)(Bt + (long)z * sB);

    // stage K-tile k0 into slot: linear LDS dest, inverse-swizzled global src
    auto stage = [&](int k0, int slot) {
        char* base = smem + slot * 65536;
        #pragma unroll
        for (int i = 0; i < 4; ++i) {
            const int d = i * 8192 + t * 16;
            const int row = d >> 7;
            const int cb = (d & 127) ^ ((row & 7) << 4);
            GLD16(Azb + ((m0 + row) * (long)ldA + k0) * 2 + cb, base + d);
        }
        #pragma unroll
        for (int i = 0; i < 4; ++i) {
            const int d = i * 8192 + t * 16;
            const int row = d >> 7;
            const int cb = (d & 127) ^ ((row & 7) << 4);
            GLD16(Bzb + ((n0 + row) * (long)ldB + k0) * 2 + cb, base + 32768 + d);
        }
    };

    f32x4 acc[8][4] = {};
    const int nK = K >> 6;
    stage(0, 0);

    for (int tk = 0; tk < nK; ++tk) {
        const int s = tk & 1;
        asm volatile("s_waitcnt vmcnt(0)" ::: "memory");   // own staging of slot s done
        SBAR();
        __builtin_amdgcn_s_barrier();                      // everyone's staging done
        SBAR();
        if (tk + 1 < nK) stage((tk + 1) << 6, s ^ 1);      // issue next tile early
        SBAR();

        const char* As = smem + s * 65536;
        const char* Bs = As + 32768;
        auto rdA = [&](int mi, int kk) {
            const int row = wr * 128 + mi * 16 + r16;
            return *reinterpret_cast<const bf16x8*>(
                As + ((row * 128 + kk * 64 + q * 16) ^ ((row & 7) << 4)));
        };
        auto rdB = [&](int ni, int kk) {
            const int row = wc * 64 + ni * 16 + r16;
            return *reinterpret_cast<const bf16x8*>(
                Bs + ((row * 128 + kk * 64 + q * 16) ^ ((row & 7) << 4)));
        };

        bf16x8 a0[4], a1[4], b0[4], b1[4];
        #pragma unroll
        for (int i = 0; i < 4; ++i) b0[i] = rdB(i, 0);
        #pragma unroll
        for (int i = 0; i < 4; ++i) a0[i] = rdA(i, 0);
        #pragma unroll
        for (int i = 0; i < 4; ++i) a1[i] = rdA(4 + i, 0);
        WAIT_LGKM(4);                                  // b0,a0 ready (a1 in flight)
        __builtin_amdgcn_s_setprio(1);
        #pragma unroll
        for (int mi = 0; mi < 4; ++mi)
            #pragma unroll
            for (int ni = 0; ni < 4; ++ni)
                acc[mi][ni] = __builtin_amdgcn_mfma_f32_16x16x32_bf16(
                    a0[mi], b0[ni], acc[mi][ni], 0, 0, 0);
        __builtin_amdgcn_s_setprio(0);
        SBAR();
        #pragma unroll
        for (int i = 0; i < 4; ++i) b1[i] = rdB(i, 1);
        #pragma unroll
        for (int i = 0; i < 4; ++i) a0[i] = rdA(i, 1);     // reuse regs (anti-dep ok)
        WAIT_LGKM(8);                                  // a1 ready (b1,a0' in flight)
        __builtin_amdgcn_s_setprio(1);
        #pragma unroll
        for (int mi = 0; mi < 4; ++mi)
            #pragma unroll
            for (int ni = 0; ni < 4; ++ni)
                acc[4 + mi][ni] = __builtin_amdgcn_mfma_f32_16x16x32_bf16(
                    a1[mi], b0[ni], acc[4 + mi][ni], 0, 0, 0);
        __builtin_amdgcn_s_setprio(0);
        SBAR();
        #pragma unroll
        for (int i = 0; i < 4; ++i) a1[i] = rdA(4 + i, 1);
        WAIT_LGKM(4);                                  // b1,a0' ready (a1' in flight)
        __builtin_amdgcn_s_setprio(1);
        #pragma unroll
        for (int mi = 0; mi < 4; ++mi)
            #pragma unroll
            for (int ni = 0; ni < 4; ++ni)
                acc[mi][ni] = __builtin_amdgcn_mfma_f32_16x16x32_bf16(
                    a0[mi], b1[ni], acc[mi][ni], 0, 0, 0);
        __builtin_amdgcn_s_setprio(0);
        SBAR();
        WAIT_LGKM(0);                                  // a1' ready
        __builtin_amdgcn_s_setprio(1);
        #pragma unroll
        for (int mi = 0; mi < 4; ++mi)
            #pragma unroll
            for (int ni = 0; ni < 4; ++ni)
                acc[4 + mi][ni] = __builtin_amdgcn_mfma_f32_16x16x32_bf16(
                    a1[mi], b1[ni], acc[4 + mi][ni], 0, 0, 0);
        __builtin_amdgcn_s_setprio(0);
        SBAR();
    }

    const float alpha = (OUT_MODE == 3) ? alphap[0] : 0.0f;
    #pragma unroll
    for (int mi = 0; mi < 8; ++mi) {
        #pragma unroll
        for (int ni = 0; ni < 4; ++ni) {
            #pragma unroll
            for (int r = 0; r < 4; ++r) {
                const long row = m0 + wr * 128 + mi * 16 + q * 4 + r;
                const long col = n0 + wc * 64 + ni * 16 + r16;
                float vv = acc[mi][ni][r];
                if (BIAS_MODE == 1) vv += bias[col];
                if (BIAS_MODE == 2) vv += bias[row];
                if (OUT_MODE == 0) {
                    ((__hip_bfloat16*)outp)[(long)z * sC + row * ldC + col] = __float2bfloat16(vv);
                } else if (OUT_MODE == 1) {
                    ((float*)outp)[(long)z * sC + row * ldC + col] = vv;
                } else if (OUT_MODE == 2) {
                    const long addr = (col >> 8) * (long)(kC * kHW) + row * kHW + (col & 255);
                    ((__hip_bfloat16*)outp)[addr] = __float2bfloat16(vv);
                } else {
                    const long addr = (col >> 8) * (long)(kC * kHW) + row * kHW + (col & 255);
                    ((float*)outp)[addr] = alpha * vv + resid[addr];
                }
            }
        }
    }
}

// x (B, C, HW) f32  ->  xT (B*HW, C) bf16
__global__ __launch_bounds__(256) void transpose_x(
    const float* __restrict__ x, __hip_bfloat16* __restrict__ xT)
{
    __shared__ float tile[64][65];
    const int b = blockIdx.z;
    const int c0 = blockIdx.x * 64;
    const int p0 = blockIdx.y * 64;
    const int tj = threadIdx.x & 63;
    const int ti = threadIdx.x >> 6;
    const float* xb = x + ((long)b * kC + c0) * kHW + p0;
    #pragma unroll
    for (int i = 0; i < 16; ++i) {
        const int c = i * 4 + ti;
        tile[c][tj] = xb[(long)c * kHW + tj];
    }
    __syncthreads();
    __hip_bfloat16* o = xT + ((long)(b * kHW + p0)) * kC + c0;
    #pragma unroll
    for (int i = 0; i < 16; ++i) {
        const int p = i * 4 + ti;
        o[(long)p * kC + tj] = __float2bfloat16(tile[tj][p]);
    }
}

__global__ __launch_bounds__(256) void convert_f32_bf16(
    const float* __restrict__ s, __hip_bfloat16* __restrict__ d)
{
    const int i = (blockIdx.x * 256 + threadIdx.x) * 4;
    const float4 f = *reinterpret_cast<const float4*>(s + i);
    d[i + 0] = __float2bfloat16(f.x);
    d[i + 1] = __float2bfloat16(f.y);
    d[i + 2] = __float2bfloat16(f.z);
    d[i + 3] = __float2bfloat16(f.w);
}

__global__ __launch_bounds__(256) void concat_bias(
    const float* __restrict__ bk, const float* __restrict__ bq, float* __restrict__ bc)
{
    const int i = blockIdx.x * 256 + threadIdx.x;  // grid 10*256 = 2560
    bc[i] = (i < 1280) ? bk[i] : bq[i - 1280];
}

// softmax over BATCH axis: scores (B,256,256) f32 -> attn bf16
__global__ __launch_bounds__(256) void softmax_batch(
    const float* __restrict__ scores, __hip_bfloat16* __restrict__ attn)
{
    const int pos = blockIdx.x * 256 + threadIdx.x;
    float m = -3.0e38f, s = 0.0f;
    for (int b = 0; b < kB; ++b) {
        const float v = scores[(long)b * 65536 + pos];
        const float mn = fmaxf(m, v);
        s = s * __expf(m - mn) + __expf(v - mn);
        m = mn;
    }
    const float rinv = 1.0f / s;
    for (int b = 0; b < kB; ++b) {
        const float v = scores[(long)b * 65536 + pos];
        attn[(long)b * 65536 + pos] = __float2bfloat16(__expf(v - m) * rinv);
    }
}

extern "C" void kernel_launch(void* const* d_in, const int* in_sizes, int n_in,
                              void* d_out, int out_size, void* d_ws, size_t ws_size,
                              hipStream_t stream)
{
    const float* x  = (const float*)d_in[0];
    const float* Wk = (const float*)d_in[1];
    const float* bk = (const float*)d_in[2];
    const float* Wq = (const float*)d_in[3];
    const float* bq = (const float*)d_in[4];
    const float* Wv = (const float*)d_in[5];
    const float* bv = (const float*)d_in[6];
    const float* Wr = (const float*)d_in[7];
    const float* br = (const float*)d_in[8];
    const float* al = (const float*)d_in[9];

    char* ws = (char*)d_ws;
    __hip_bfloat16* xT   = (__hip_bfloat16*)(ws);               // 83.9MB; dead after V GEMM
    float*          sc   = (float*)(ws);                        // aliases xT (33.5MB)
    __hip_bfloat16* kqT  = (__hip_bfloat16*)(ws + 83886080L);   // (32768,2560) 167.8MB
    __hip_bfloat16* attn = (__hip_bfloat16*)(ws + 83886080L);   // aliases kqT (16.8MB)
    __hip_bfloat16* att2 = (__hip_bfloat16*)(ws + 100663296L);  // aliases kqT tail (83.9MB)
    __hip_bfloat16* vv   = (__hip_bfloat16*)(ws + 251658240L);  // 83.9MB
    __hip_bfloat16* Wcatb= (__hip_bfloat16*)(ws + 335544320L);  // (2560,1280)
    __hip_bfloat16* Wvb  = Wcatb + 2560 * 1280;
    __hip_bfloat16* Wrb  = Wvb + 1280 * 1280;
    float*          bcat = (float*)(ws + 348651520L);           // 2560 f32

    const int SMEM = 131072;
    hipFuncSetAttribute((const void*)gemm_q<0,1,1>, hipFuncAttributeMaxDynamicSharedMemorySize, SMEM);
    hipFuncSetAttribute((const void*)gemm_q<2,2,0>, hipFuncAttributeMaxDynamicSharedMemorySize, SMEM);
    hipFuncSetAttribute((const void*)gemm_q<1,0,0>, hipFuncAttributeMaxDynamicSharedMemorySize, SMEM);
    hipFuncSetAttribute((const void*)gemm_q<0,0,0>, hipFuncAttributeMaxDynamicSharedMemorySize, SMEM);
    hipFuncSetAttribute((const void*)gemm_q<3,2,0>, hipFuncAttributeMaxDynamicSharedMemorySize, SMEM);

    convert_f32_bf16<<<1600, 256, 0, stream>>>(Wk, Wcatb);
    convert_f32_bf16<<<1600, 256, 0, stream>>>(Wq, Wcatb + 1638400);
    convert_f32_bf16<<<1600, 256, 0, stream>>>(Wv, Wvb);
    convert_f32_bf16<<<1600, 256, 0, stream>>>(Wr, Wrb);
    concat_bias<<<10, 256, 0, stream>>>(bk, bq, bcat);
    transpose_x<<<dim3(20, 4, 128), 256, 0, stream>>>(x, xT);

    // fused K|Q: kqT (32768, 2560) = xT * Wcat^T + bcat[col]; A large -> ORDER=1
    gemm_q<0, 1, 1><<<dim3(1280, 1, 1), 512, SMEM, stream>>>(xT, Wcatb, kqT, bcat, nullptr, nullptr,
        32768, 2560, 1280, 1280, 1280, 0, 0, 0, 2560);
    // v (B,C,HW) = Wv * xT^T + bv[row];  B large -> ORDER=0
    gemm_q<2, 2, 0><<<dim3(640, 1, 1), 512, SMEM, stream>>>(Wvb, xT, vv, bv, nullptr, nullptr,
        1280, 32768, 1280, 1280, 1280, 0, 0, 0, 0);
    // scores (B,256,256) f32 = kT[b] * qT[b]^T
    gemm_q<1, 0, 0><<<dim3(1, 1, 128), 512, SMEM, stream>>>(kqT, kqT + 1280, sc, nullptr, nullptr, nullptr,
        256, 256, 1280, 2560, 2560, 655360, 655360, 65536, 256);
    softmax_batch<<<256, 256, 0, stream>>>(sc, attn);
    // att2 (B,256,1280) = attn[b] * v[b]^T
    gemm_q<0, 0, 0><<<dim3(5, 1, 128), 512, SMEM, stream>>>(attn, vv, att2, nullptr, nullptr, nullptr,
        256, 1280, 256, 256, 256, 65536, 327680, 327680, 1280);
    // out f32 (B,C,HW) = alpha*(Wr*att2^T + br[row]) + x;  B large -> ORDER=0
    gemm_q<3, 2, 0><<<dim3(640, 1, 1), 512, SMEM, stream>>>(Wrb, att2, d_out, br, x, al,
        1280, 32768, 1280, 1280, 1280, 0, 0, 0, 0);
}